// Round 7
// baseline (157.895 us; speedup 1.0000x reference)
//
#include <hip/hip_runtime.h>

typedef unsigned short u16;
typedef __attribute__((ext_vector_type(8))) short s16x8;
typedef __attribute__((ext_vector_type(4))) float f32x4;
typedef __attribute__((ext_vector_type(4))) unsigned int u32x4;

// f32 -> bf16 bits, round-to-nearest-even (finite values)
__device__ __forceinline__ u16 f2bf(float f) {
    unsigned u = __builtin_bit_cast(unsigned, f);
    u += 0x7fffu + ((u >> 16) & 1u);
    return (u16)(u >> 16);
}
__device__ __forceinline__ float lo_bf(unsigned v) {
    return __builtin_bit_cast(float, v << 16);
}
__device__ __forceinline__ float hi_bf(unsigned v) {
    return __builtin_bit_cast(float, v & 0xffff0000u);
}

// LGKM-only barrier: orders LDS traffic across the workgroup WITHOUT draining
// vmcnt — global stores stay in flight across phases (R6-verified correct).
__device__ __forceinline__ void bar_lgkm() {
    __builtin_amdgcn_sched_barrier(0);
    asm volatile("s_waitcnt lgkmcnt(0)" ::: "memory");
    __builtin_amdgcn_s_barrier();
    __builtin_amdgcn_sched_barrier(0);
}

// ws layout (floats): [0..127] Sx[n][c], [128..255] Sx2[n][c]
#define WS_SX   0
#define WS_SX2  128

// ---------------- Kernel 1: per-(n,c) moments of x (fp32) ----------------
__global__ __launch_bounds__(256) void k_reduce(const float* __restrict__ x,
                                                float* __restrict__ ws) {
    int nc = blockIdx.x;                       // 0..127, one 4096-elem channel each
    const f32x4* p = (const f32x4*)(x + (size_t)nc * 4096);
    int t = threadIdx.x;
    float s = 0.f, s2 = 0.f;
    for (int it = 0; it < 4; ++it) {
        f32x4 v = p[t + it * 256];
        for (int e = 0; e < 4; ++e) { s += v[e]; s2 += v[e] * v[e]; }
    }
    for (int off = 32; off; off >>= 1) {
        s  += __shfl_down(s, off);
        s2 += __shfl_down(s2, off);
    }
    __shared__ float rs[4], rs2[4];
    int lane = t & 63, wv = t >> 6;
    if (lane == 0) { rs[wv] = s; rs2[wv] = s2; }
    __syncthreads();
    if (t == 0) {
        ws[WS_SX  + nc] = rs[0] + rs[1] + rs[2] + rs[3];
        ws[WS_SX2 + nc] = rs2[0] + rs2[1] + rs2[2] + rs2[3];
    }
}

// ---------------- Kernel 2: fused stats + upsample + GN + pointwise --------
// Round 7: o-plane-major decomposition. Block = (n, og, dd):
//   og in [0,4) -> o-group of 16; dd in [0,64) -> one full output depth-row
//   (d = dd>>2, i = dd&3 fixed). Block writes out[n, o in og*16+[0,16), dd, :, :]
//   = 16 regions of 16 KiB, each FULLY CONTIGUOUS, emitted as 16 sequential
//   1 KiB wave stores. Device-wide: 8K write streams x 16 KiB spans
//   (vs 32K x 1-4 KiB in R2/R3/R6) -> L2 dirty-eviction order becomes
//   stream-local, DRAM sees long bursts (the fill-kernel regime).
// Per chunk qc in [0,16): h = qc, wave wid = j; q covers hh = 4*qc+wid, all ww.
// Arithmetic per element identical to R0-R6 (absmax must stay 0.046875).
#define SWS 72       // LDS row stride in shorts (144 B, 16B-aligned)
#define STG_LD 260   // staging row stride in floats (1040 B)
__global__ __launch_bounds__(256, 2) void k_main(const float* __restrict__ x,
                                              const float* __restrict__ w_ct,
                                              const float* __restrict__ b_ct,
                                              const float* __restrict__ gamma,
                                              const float* __restrict__ beta,
                                              const float* __restrict__ w_pw,
                                              const float* __restrict__ ws,
                                              float* __restrict__ out) {
    __shared__ __align__(16) u16   sWb[16 * SWS];   // [j*4+k][c] bf16, i = i_f slice (2.25 KiB)
    __shared__ __align__(16) u16   sXb[256 * SWS];  // [h*16+w][c] bf16 (36 KiB)
    __shared__ __align__(16) float stg[16 * STG_LD];// [o_loc][q=256] staging (16.6 KiB)
    __shared__ float p_sw[256], p_sw2[256];         // partial w-moments [qr][c]
    __shared__ float s_b[64], s_g[64], s_be[64];
    __shared__ float sK[16];
    __shared__ float s_mi[2];                       // mean, inv_std

    float* sA = stg;   // [16 o][c] fp32, stride 68 (1088 floats) — dead before stg use

    int t = threadIdx.x;
    int b = blockIdx.x;
    int n = b >> 8, og = (b >> 6) & 3, dd = b & 63;
    int d = dd >> 2, i_f = dd & 3;

    // ---- stage w_ct stats (all 64 ijk) + the i_f slice to LDS ----
    {
        int c = t & 63, qr = t >> 6;               // 4 threads per channel
        const f32x4* wp = (const f32x4*)(w_ct + c * 64 + qr * 16);
        float sw = 0.f, sw2 = 0.f;
        for (int r = 0; r < 4; ++r) {
            f32x4 v = wp[r];
            for (int e = 0; e < 4; ++e) {
                float f = v[e];
                sw += f; sw2 += f * f;
                if (qr == i_f) sWb[(r * 4 + e) * SWS + c] = f2bf(f);
            }
        }
        p_sw[t] = sw; p_sw2[t] = sw2;
    }
    // ---- stage x[n, c, d, :, :]: c = t&63, quarter qr = t>>6 (64 floats each) ----
    {
        int c = t & 63, qr = t >> 6;
        const f32x4* xp = (const f32x4*)(x + ((size_t)n * 64 + c) * 4096 + d * 256 + qr * 64);
        for (int r = 0; r < 16; ++r) {
            f32x4 v = xp[r];
            for (int e = 0; e < 4; ++e)
                sXb[(qr * 64 + r * 4 + e) * SWS + c] = f2bf(v[e]);
        }
    }
    if (t < 64) { s_b[t] = b_ct[t]; s_g[t] = gamma[t]; s_be[t] = beta[t]; }
    __syncthreads();

    // ---- analytic GroupNorm stats (wave 0) ----
    if (t < 64) {
        int c = t;
        float sw  = p_sw[c]  + p_sw[64 + c]  + p_sw[128 + c]  + p_sw[192 + c];
        float sw2 = p_sw2[c] + p_sw2[64 + c] + p_sw2[128 + c] + p_sw2[192 + c];
        float sx  = ws[WS_SX  + n * 64 + c];
        float sx2 = ws[WS_SX2 + n * 64 + c];
        float bc  = s_b[c];
        float ty  = sw  * sx  + 262144.f * bc;
        float ty2 = sw2 * sx2 + 2.f * bc * sw * sx + 262144.f * bc * bc;
        for (int off = 32; off; off >>= 1) {
            ty  += __shfl_down(ty, off);
            ty2 += __shfl_down(ty2, off);
        }
        if (t == 0) {
            float mean = ty * (1.f / 16777216.f);
            float var  = ty2 * (1.f / 16777216.f) - mean * mean;
            s_mi[0] = mean;
            s_mi[1] = rsqrtf(var + 1e-5f);
        }
    }
    __syncthreads();

    float mean = s_mi[0], inv = s_mi[1];
    // ---- A[oo][c] = w_pw[og*16+oo, c] * gamma[c] * inv  (16 o only) ----
    for (int k = 0; k < 4; ++k) {
        int idx = k * 256 + t;                     // 0..1023 over the og panel
        int c = idx & 63;
        sA[(idx >> 6) * 68 + c] = w_pw[og * 1024 + idx] * s_g[c] * inv;
    }
    // ---- K[oo] = sum_c w_pw[o,c] * (g[c]*inv*(b[c]-mean) + beta[c]) ----
    if (t < 16) {
        int o = og * 16 + t;
        const f32x4* wp = (const f32x4*)(w_pw + o * 64);
        float k = 0.f;
        for (int r = 0; r < 16; ++r) {
            f32x4 v = wp[r];
            for (int e = 0; e < 4; ++e) {
                int c = r * 4 + e;
                k += v[e] * (s_g[c] * inv * (s_b[c] - mean) + s_be[c]);
            }
        }
        sK[t] = k;
    }
    __syncthreads();

    int lane = t & 63;
    int wid  = t >> 6;          // wave id = j
    int colq = lane & 15;
    int quad = lane >> 4;

    // ---- A fragments (b-operand): lane holds A[oo=colq][c=kt*32+quad*8+j] ----
    s16x8 afrag[2];
    for (int kt = 0; kt < 2; ++kt) {
        int c0 = kt * 32 + quad * 8;
        const float* ap = &sA[colq * 68 + c0];
        f32x4 f0 = *(const f32x4*)ap;
        f32x4 f1 = *(const f32x4*)(ap + 4);
        s16x8 fr;
        fr[0] = (short)f2bf(f0[0]); fr[1] = (short)f2bf(f0[1]);
        fr[2] = (short)f2bf(f0[2]); fr[3] = (short)f2bf(f0[3]);
        fr[4] = (short)f2bf(f1[0]); fr[5] = (short)f2bf(f1[1]);
        fr[6] = (short)f2bf(f1[2]); fr[7] = (short)f2bf(f1[3]);
        afrag[kt] = fr;
    }
    f32x4 kinit;
    {
        float kv = sK[colq];
        kinit[0] = kv; kinit[1] = kv; kinit[2] = kv; kinit[3] = kv;
    }
    __syncthreads();   // sA (aliased with stg) fully consumed by all waves

    size_t obase = ((size_t)n << 24) + ((size_t)(og * 16) << 18) + (size_t)dd * 4096;

    // ---- 16 chunks: chunk qc covers hh = 4*qc + j (j = wid), all ww ----
    for (int qc = 0; qc < 16; ++qc) {
        // -- compute phase: 4 W-tiles -> stg[16 o][256 q] --
        #pragma unroll
        for (int tt = 0; tt < 4; ++tt) {
            int Woff = tt * 16 + colq;
            int wi   = Woff >> 2;
            int kf   = Woff & 3;
            int wrow = wid * 4 + kf;               // j*4+k within the i_f slice
            int xrow = qc * 16 + wi;               // h*16+w

            s16x8 bfrag[2];
            #pragma unroll
            for (int kt = 0; kt < 2; ++kt) {
                int c0 = kt * 32 + quad * 8;
                u32x4 wv = *(const u32x4*)&sWb[wrow * SWS + c0];
                u32x4 xv = *(const u32x4*)&sXb[xrow * SWS + c0];
                s16x8 fr;
                for (int e = 0; e < 4; ++e) {
                    float pl = lo_bf(wv[e]) * lo_bf(xv[e]);
                    float ph = hi_bf(wv[e]) * hi_bf(xv[e]);
                    fr[2 * e]     = (short)f2bf(pl);
                    fr[2 * e + 1] = (short)f2bf(ph);
                }
                bfrag[kt] = fr;
            }
            f32x4 a = kinit;
            a = __builtin_amdgcn_mfma_f32_16x16x32_bf16(bfrag[0], afrag[0], a, 0, 0, 0);
            a = __builtin_amdgcn_mfma_f32_16x16x32_bf16(bfrag[1], afrag[1], a, 0, 0, 0);
            // stg[oo = colq][q = j*64 + tt*16 + quad*4 + {0..3}]
            int q_loc = wid * 64 + tt * 16 + quad * 4;
            *(f32x4*)&stg[colq * STG_LD + q_loc] = a;
        }
        bar_lgkm();    // stg visible; global stores from prior chunks still in flight

        // -- store phase: 16 o x 1 KiB, each o's installment SEQUENTIAL in qc --
        size_t gq = (size_t)(qc * 256 + lane * 4);
        #pragma unroll
        for (int it = 0; it < 4; ++it) {
            int o_loc = it * 4 + wid;
            f32x4 v = *(const f32x4*)&stg[o_loc * STG_LD + lane * 4];
            *(f32x4*)(out + obase + ((size_t)o_loc << 18) + gq) = v;
        }
        bar_lgkm();    // stg reads done -> safe to rewrite; vmcnt NOT drained
    }
}

extern "C" void kernel_launch(void* const* d_in, const int* in_sizes, int n_in,
                              void* d_out, int out_size, void* d_ws, size_t ws_size,
                              hipStream_t stream) {
    const float* x     = (const float*)d_in[0];
    const float* w_ct  = (const float*)d_in[1];
    const float* b_ct  = (const float*)d_in[2];
    const float* gamma = (const float*)d_in[3];
    const float* beta  = (const float*)d_in[4];
    const float* w_pw  = (const float*)d_in[5];
    float* ws  = (float*)d_ws;
    float* out = (float*)d_out;

    k_reduce<<<128, 256, 0, stream>>>(x, ws);
    k_main<<<512, 256, 0, stream>>>(x, w_ct, b_ct, gamma, beta, w_pw, ws, out);
}